// Round 2
// baseline (6238.247 us; speedup 1.0000x reference)
//
#include <hip/hip_runtime.h>

typedef _Float16 h8 __attribute__((ext_vector_type(8)));
typedef _Float16 hv4 __attribute__((ext_vector_type(4)));
typedef float f4 __attribute__((ext_vector_type(4)));

#define SEQ_LEN 50
#define HID 64
#define HSTRIDE 76  // halves; 152B row pitch -> conflict-free b64 A-frag reads

#if __has_builtin(__builtin_amdgcn_exp2f)
#define EXP2(x) __builtin_amdgcn_exp2f(x)
#else
extern "C" __device__ float __ocml_native_exp2_f32(float);
#define EXP2(x) __ocml_native_exp2_f32(x)
#endif
#define RCP(x) __builtin_amdgcn_rcpf(x)

#define LOG2E  1.442695041f
#define LOG2E2 2.885390082f

// v pre-scaled by log2e: sigmoid(v/log2e) = 1/(1+2^-v)
__device__ __forceinline__ float sig2(float v) {
    return RCP(1.0f + EXP2(-v));
}
// v pre-scaled by 2*log2e: tanh(v/(2 log2e)) = 1 - 2/(1+2^v)
__device__ __forceinline__ float tanh2(float v) {
    return 1.0f - 2.0f * RCP(1.0f + EXP2(v));
}

// Block = 128 threads = 2 waves, owns 16 sequences.
// Wave w computes n-tiles {g*4 + 2w + d : g in 0..3 (i,f,g,o), d in 0..1},
// i.e. gate values for units u = 32w .. 32w+31 of all 16 sequences.
// C-layout (16x16x32): col = lane&15 (n within tile), row = quad*4 + reg (seq).
// Tiles processed in two groups by d: i/f/g/o for one unit share d, so each
// group needs only 4 live accumulators (16 VGPRs) -> combined regs <= 128
// -> 4 waves/SIMD.
__global__ __launch_bounds__(128, 4)
void lstm_fused(const float* __restrict__ x,
                const float* __restrict__ W_ih,
                const float* __restrict__ W_hh,
                const float* __restrict__ b_ih,
                const float* __restrict__ b_hh,
                const float* __restrict__ W_fc,
                const float* __restrict__ b_fc,
                float* __restrict__ out)
{
    __shared__ _Float16 sH[2][16 * HSTRIDE];  // h double-buffer, fp16
    __shared__ float    sX[16 * SEQ_LEN];     // staged x tile, fp32

    const int tid  = threadIdx.x;
    const int wave = tid >> 6;
    const int lane = tid & 63;
    const int col  = lane & 15;
    const int quad = lane >> 4;
    const int seqBase = blockIdx.x << 4;

    // ---- stage x: 16 seqs x 50 floats = 800 floats, contiguous & 16B-aligned
    {
        const f4* gx = (const f4*)(x + (size_t)seqBase * SEQ_LEN);
        f4* sx = (f4*)sX;
        #pragma unroll
        for (int i = 0; i < 2; ++i) {
            int idx = tid + i * 128;
            if (idx < (16 * SEQ_LEN) / 4) sx[idx] = gx[idx];
        }
    }
    // ---- zero both h buffers (h0 = 0)
    for (int i = tid; i < 2 * 16 * HSTRIDE; i += 128)
        ((_Float16*)sH)[i] = (_Float16)0.0f;

    // ---- W_hh as resident fp16 B-fragments, PRE-SCALED by log2e (i,f,o rows)
    // or 2*log2e (g rows) so activations use raw v_exp_f32 with no mul.
    h8 Bf[8][2];
    float wih[8], bs[8];
    #pragma unroll
    for (int g = 0; g < 4; ++g) {
        const float scale = (g == 2) ? LOG2E2 : LOG2E;
        #pragma unroll
        for (int d = 0; d < 2; ++d) {
            const int tt = g * 2 + d;
            const int n  = (g * 4 + 2 * wave + d) * 16 + col;
            wih[tt] = W_ih[n] * scale;
            bs[tt]  = (b_ih[n] + b_hh[n]) * scale;
            #pragma unroll
            for (int kf = 0; kf < 2; ++kf) {
                const float* wp = W_hh + n * HID + kf * 32 + quad * 8;
                f4 lo = *(const f4*)wp;
                f4 hi = *(const f4*)(wp + 4);
                h8 b;
                b[0] = (_Float16)(lo[0] * scale); b[1] = (_Float16)(lo[1] * scale);
                b[2] = (_Float16)(lo[2] * scale); b[3] = (_Float16)(lo[3] * scale);
                b[4] = (_Float16)(hi[0] * scale); b[5] = (_Float16)(hi[1] * scale);
                b[6] = (_Float16)(hi[2] * scale); b[7] = (_Float16)(hi[3] * scale);
                Bf[tt][kf] = b;
            }
        }
    }

    float c[2][4];
    #pragma unroll
    for (int d = 0; d < 2; ++d)
        #pragma unroll
        for (int r = 0; r < 4; ++r) c[d][r] = 0.0f;

    __syncthreads();

    #pragma unroll 2
    for (int t = 0; t < SEQ_LEN; ++t) {
        const _Float16* hb = sH[t & 1];
        _Float16*       hw = sH[(t + 1) & 1];

        // x_t for this lane's 4 rows (broadcast ds_read, conflict-free)
        float xq[4];
        #pragma unroll
        for (int r = 0; r < 4; ++r) xq[r] = sX[(quad * 4 + r) * SEQ_LEN + t];

        // A-fragments of current h (two b64 reads each; 152B pitch -> no conflicts)
        h8 A[2];
        #pragma unroll
        for (int kf = 0; kf < 2; ++kf) {
            const _Float16* p = hb + col * HSTRIDE + kf * 32 + quad * 8;
            hv4 a0 = *(const hv4*)p;
            hv4 a1 = *(const hv4*)(p + 4);
            A[kf] = __builtin_shufflevector(a0, a1, 0, 1, 2, 3, 4, 5, 6, 7);
        }

        // Two groups of 4 tiles (d = 0,1): only 4 f4 accumulators live at once,
        // and group-0 activations (trans pipe) overlap group-1 MFMAs.
        #pragma unroll
        for (int d = 0; d < 2; ++d) {
            f4 acc[4];
            #pragma unroll
            for (int g4 = 0; g4 < 4; ++g4) {
                const int tt = g4 * 2 + d;
                f4 a;
                #pragma unroll
                for (int r = 0; r < 4; ++r) a[r] = fmaf(xq[r], wih[tt], bs[tt]);
                a = __builtin_amdgcn_mfma_f32_16x16x32_f16(A[0], Bf[tt][0], a, 0, 0, 0);
                a = __builtin_amdgcn_mfma_f32_16x16x32_f16(A[1], Bf[tt][1], a, 0, 0, 0);
                acc[g4] = a;
            }
            #pragma unroll
            for (int r = 0; r < 4; ++r) {
                float ig = sig2(acc[0][r]);
                float fg = sig2(acc[1][r]);
                float gg = tanh2(acc[2][r]);
                float og = sig2(acc[3][r]);
                float cc = fmaf(fg, c[d][r], ig * gg);
                c[d][r] = cc;
                float hh = og * tanh2(cc * LOG2E2);
                hw[(quad * 4 + r) * HSTRIDE + 32 * wave + d * 16 + col] = (_Float16)hh;
            }
        }
        __syncthreads();
    }

    // ---- epilogue: final h is in sH[0] (t=49 wrote buffer (49+1)&1 = 0)
    if (lane < 24) {
        const int sl = wave * 8 + lane / 3;  // sequence within tile
        const int nc = lane % 3;             // class
        const _Float16* hp = sH[0] + sl * HSTRIDE;
        float a = b_fc[nc];
        #pragma unroll
        for (int u = 0; u < HID; ++u)
            a = fmaf((float)hp[u], W_fc[nc * HID + u], a);
        out[(size_t)(seqBase + sl) * 3 + nc] = a;
    }
}

extern "C" void kernel_launch(void* const* d_in, const int* in_sizes, int n_in,
                              void* d_out, int out_size, void* d_ws, size_t ws_size,
                              hipStream_t stream) {
    const float* x    = (const float*)d_in[0];
    const float* W_ih = (const float*)d_in[1];
    const float* W_hh = (const float*)d_in[2];
    const float* b_ih = (const float*)d_in[3];
    const float* b_hh = (const float*)d_in[4];
    const float* W_fc = (const float*)d_in[5];
    const float* b_fc = (const float*)d_in[6];
    float* out = (float*)d_out;

    const int nSeq   = in_sizes[0] / SEQ_LEN;  // 512000
    const int blocks = nSeq / 16;              // 32000

    hipLaunchKernelGGL(lstm_fused, dim3(blocks), dim3(128), 0, stream,
                       x, W_ih, W_hh, b_ih, b_hh, W_fc, b_fc, out);
}

// Round 3
// 2406.020 us; speedup vs baseline: 2.5928x; 2.5928x over previous
//
#include <hip/hip_runtime.h>

typedef _Float16 h8 __attribute__((ext_vector_type(8)));
typedef _Float16 hv4 __attribute__((ext_vector_type(4)));
typedef float f4 __attribute__((ext_vector_type(4)));

#define SEQ_LEN 50
#define HID 64
#define HSTRIDE 76  // halves; 152B row pitch -> conflict-free b64 A-frag reads

#if __has_builtin(__builtin_amdgcn_exp2f)
#define EXP2(x) __builtin_amdgcn_exp2f(x)
#else
extern "C" __device__ float __ocml_native_exp2_f32(float);
#define EXP2(x) __ocml_native_exp2_f32(x)
#endif
#define RCP(x) __builtin_amdgcn_rcpf(x)

#define LOG2E  1.442695041f
#define LOG2E2 2.885390082f

// v pre-scaled by log2e: sigmoid(v/log2e) = 1/(1+2^-v)
__device__ __forceinline__ float sig2(float v) {
    return RCP(1.0f + EXP2(-v));
}
// v pre-scaled by 2*log2e: returns LOG2E2 * tanh(v/(2 log2e))
// (keeps the cell state in the scaled domain -> no mul before the h-tanh)
__device__ __forceinline__ float tanh2s(float v) {
    return fmaf(RCP(1.0f + EXP2(v)), -2.0f * LOG2E2, LOG2E2);
}
// v pre-scaled by 2*log2e: plain tanh(v/(2 log2e))
__device__ __forceinline__ float tanh2(float v) {
    return 1.0f - 2.0f * RCP(1.0f + EXP2(v));
}

// Block = 128 threads = 2 waves, owns 16 sequences.
// Wave w computes n-tiles {g*4 + 2w + d : g in 0..3 (i,f,g,o), d in 0..1},
// i.e. gate values for units u = 32w .. 32w+31 of all 16 sequences.
// C-layout (16x16x32): col = lane&15 (n within tile), row = quad*4 + reg (seq).
// Tiles processed in two groups by d (4 live accumulators each).
// Register demand ~135 combined VGPR+AGPR: fits 3 waves/SIMD (budget ~170).
// 4 waves/SIMD (budget 128) SPILLS W_hh to scratch -> 24 GB HBM traffic (R2).
__global__ __launch_bounds__(128, 3)
void lstm_fused(const float* __restrict__ x,
                const float* __restrict__ W_ih,
                const float* __restrict__ W_hh,
                const float* __restrict__ b_ih,
                const float* __restrict__ b_hh,
                const float* __restrict__ W_fc,
                const float* __restrict__ b_fc,
                float* __restrict__ out)
{
    __shared__ _Float16 sH[2][16 * HSTRIDE];  // h double-buffer, fp16
    __shared__ float    sXT[SEQ_LEN * 16];    // x tile, TRANSPOSED [t][seq]

    const int tid  = threadIdx.x;
    const int wave = tid >> 6;
    const int lane = tid & 63;
    const int col  = lane & 15;
    const int quad = lane >> 4;
    const int seqBase = blockIdx.x << 4;

    // ---- stage x transposed: sXT[t*16 + s] = x[(seqBase+s)*50 + t]
    // (one step's 4 seq values per lane become a single broadcast b128 read)
    for (int i = tid; i < SEQ_LEN * 16; i += 128) {
        const int s = i & 15;
        const int t = i >> 4;
        sXT[t * 16 + s] = x[(size_t)(seqBase + s) * SEQ_LEN + t];
    }
    // ---- zero both h buffers (h0 = 0)
    for (int i = tid; i < 2 * 16 * HSTRIDE; i += 128)
        ((_Float16*)sH)[i] = (_Float16)0.0f;

    // ---- W_hh as resident fp16 B-fragments, PRE-SCALED by log2e (i,f,o rows)
    // or 2*log2e (g rows) so activations use raw v_exp_f32 with no mul.
    h8 Bf[8][2];
    float wih[8], bs[8];
    #pragma unroll
    for (int g = 0; g < 4; ++g) {
        const float scale = (g == 2) ? LOG2E2 : LOG2E;
        #pragma unroll
        for (int d = 0; d < 2; ++d) {
            const int tt = g * 2 + d;
            const int n  = (g * 4 + 2 * wave + d) * 16 + col;
            wih[tt] = W_ih[n] * scale;
            bs[tt]  = (b_ih[n] + b_hh[n]) * scale;
            #pragma unroll
            for (int kf = 0; kf < 2; ++kf) {
                const float* wp = W_hh + n * HID + kf * 32 + quad * 8;
                f4 lo = *(const f4*)wp;
                f4 hi = *(const f4*)(wp + 4);
                h8 b;
                b[0] = (_Float16)(lo[0] * scale); b[1] = (_Float16)(lo[1] * scale);
                b[2] = (_Float16)(lo[2] * scale); b[3] = (_Float16)(lo[3] * scale);
                b[4] = (_Float16)(hi[0] * scale); b[5] = (_Float16)(hi[1] * scale);
                b[6] = (_Float16)(hi[2] * scale); b[7] = (_Float16)(hi[3] * scale);
                Bf[tt][kf] = b;
            }
        }
    }

    // cell state, kept in the 2*log2e-scaled domain
    float c[2][4];
    #pragma unroll
    for (int d = 0; d < 2; ++d)
        #pragma unroll
        for (int r = 0; r < 4; ++r) c[d][r] = 0.0f;

    __syncthreads();

    #pragma unroll 2
    for (int t = 0; t < SEQ_LEN; ++t) {
        const _Float16* hb = sH[t & 1];
        _Float16*       hw = sH[(t + 1) & 1];

        // x_t for this lane's 4 rows: one broadcast ds_read_b128
        const f4 xq = *(const f4*)(sXT + t * 16 + quad * 4);

        // A-fragments of current h (two b64 reads each; 152B pitch -> no conflicts)
        h8 A[2];
        #pragma unroll
        for (int kf = 0; kf < 2; ++kf) {
            const _Float16* p = hb + col * HSTRIDE + kf * 32 + quad * 8;
            hv4 a0 = *(const hv4*)p;
            hv4 a1 = *(const hv4*)(p + 4);
            A[kf] = __builtin_shufflevector(a0, a1, 0, 1, 2, 3, 4, 5, 6, 7);
        }

        // Two groups of 4 tiles (d = 0,1): only 4 f4 accumulators live at once,
        // and group-0 activations (trans pipe) overlap group-1 MFMAs.
        #pragma unroll
        for (int d = 0; d < 2; ++d) {
            f4 acc[4];
            #pragma unroll
            for (int g4 = 0; g4 < 4; ++g4) {
                const int tt = g4 * 2 + d;
                f4 a;
                #pragma unroll
                for (int r = 0; r < 4; ++r) a[r] = fmaf(xq[r], wih[tt], bs[tt]);
                a = __builtin_amdgcn_mfma_f32_16x16x32_f16(A[0], Bf[tt][0], a, 0, 0, 0);
                a = __builtin_amdgcn_mfma_f32_16x16x32_f16(A[1], Bf[tt][1], a, 0, 0, 0);
                acc[g4] = a;
            }
            #pragma unroll
            for (int r = 0; r < 4; ++r) {
                float ig = sig2(acc[0][r]);
                float fg = sig2(acc[1][r]);
                float gg = tanh2s(acc[2][r]);   // = LOG2E2 * tanh(g)
                float og = sig2(acc[3][r]);
                float cc = fmaf(fg, c[d][r], ig * gg);  // scaled-domain cell
                c[d][r] = cc;
                float hh = og * tanh2(cc);      // input already scaled
                hw[(quad * 4 + r) * HSTRIDE + 32 * wave + d * 16 + col] = (_Float16)hh;
            }
        }
        __syncthreads();
    }

    // ---- epilogue: final h is in sH[0] (t=49 wrote buffer (49+1)&1 = 0)
    if (lane < 24) {
        const int sl = wave * 8 + lane / 3;  // sequence within tile
        const int nc = lane % 3;             // class
        const _Float16* hp = sH[0] + sl * HSTRIDE;
        float a = b_fc[nc];
        #pragma unroll
        for (int u = 0; u < HID; ++u)
            a = fmaf((float)hp[u], W_fc[nc * HID + u], a);
        out[(size_t)(seqBase + sl) * 3 + nc] = a;
    }
}

extern "C" void kernel_launch(void* const* d_in, const int* in_sizes, int n_in,
                              void* d_out, int out_size, void* d_ws, size_t ws_size,
                              hipStream_t stream) {
    const float* x    = (const float*)d_in[0];
    const float* W_ih = (const float*)d_in[1];
    const float* W_hh = (const float*)d_in[2];
    const float* b_ih = (const float*)d_in[3];
    const float* b_hh = (const float*)d_in[4];
    const float* W_fc = (const float*)d_in[5];
    const float* b_fc = (const float*)d_in[6];
    float* out = (float*)d_out;

    const int nSeq   = in_sizes[0] / SEQ_LEN;  // 512000
    const int blocks = nSeq / 16;              // 32000

    hipLaunchKernelGGL(lstm_fused, dim3(blocks), dim3(128), 0, stream,
                       x, W_ih, W_hh, b_ih, b_hh, W_fc, b_fc, out);
}